// Round 11
// baseline (313.242 us; speedup 1.0000x reference)
//
#include <hip/hip_runtime.h>

#define DEV __device__ __forceinline__

// ---- quantizer helpers (exact, round-half-even matches jnp.round) ----
DEV float qwt(float w) {
    float y = fminf(fmaxf(w, -1.0f), 0.875f);
    return rintf(y * 8.0f) * 0.125f;
}
DEV int qw8i(float w) {                       // weight -> int in [-8,7]
    float y = fminf(fmaxf(w, -1.0f), 0.875f);
    return (int)rintf(y * 8.0f);
}
DEV int q8i(float x, float a, float b) {      // act -> int in [-8,7]
    float y = fmaf(x, a, b);
    y = fminf(fmaxf(y, -1.0f), 0.875f);
    return (int)rintf(y * 8.0f);
}
DEV float qact(float x, float a, float b) {
    float y = fmaf(x, a, b);
    y = fminf(fmaxf(y, -1.0f), 0.875f);
    return rintf(y * 8.0f) * 0.125f;
}

DEV int dot4(int a, int b, int c) {
#if __has_builtin(__builtin_amdgcn_sdot4)
    return __builtin_amdgcn_sdot4(a, b, c, false);
#else
    c += (int)(signed char)(a)       * (int)(signed char)(b);
    c += (int)(signed char)(a >> 8)  * (int)(signed char)(b >> 8);
    c += (int)(signed char)(a >> 16) * (int)(signed char)(b >> 16);
    c += (int)(signed char)(a >> 24) * (int)(signed char)(b >> 24);
    return c;
#endif
}
DEV unsigned alignpair(unsigned hi, unsigned lo, int bits) {
#if __has_builtin(__builtin_amdgcn_alignbit)
    return __builtin_amdgcn_alignbit(hi, lo, bits);
#else
    return bits ? ((lo >> bits) | (hi << (32 - bits))) : lo;
#endif
}

DEV void atomAddF64(double* p, double v) { atomicAdd(p, v); }
DEV double aldD(const double* p) {
    return __hip_atomic_load(p, __ATOMIC_RELAXED, __HIP_MEMORY_SCOPE_AGENT);
}

// pack float OIHW weights -> int8x4 dwords (value*8), zero-padded past K
DEV void pack_layer(const float* w, int* o, int CIN, int COUT, int K, int t) {
    int KW = (K + 3) / 4;
    for (int i = t; i < COUT * CIN * KW; i += 256) {
        int j = i % KW, cc = i / KW;
        unsigned r = 0;
        for (int u = 0; u < 4; u++) {
            int k = 4 * j + u;
            int b = (k < K) ? (qw8i(w[cc * K + k]) & 0xff) : 0;
            r |= (unsigned)b << (8 * u);
        }
        o[i] = (int)r;
    }
}

// ---------------------------------------------------------------------------
// int8/dot4 1-D strided conv (stride 2, VALID). R10-proven: vb-loop grid
// 1024, 4-deep staging prefetch, block-lifetime tsum/tsq with ONE butterfly
// + slot atomic per block (slot bid&7).
// ---------------------------------------------------------------------------
template<int CIN,int COUT,int K,int LINP,int LOUT,int LOUTP,int P,int R,bool IN_FLOAT,int LIN=0>
DEV void conv_phase(
    const void* __restrict__ in_, const int* __restrict__ wqi,
    const double* __restrict__ statsIn,
    const float* __restrict__ gprev, const float* __restrict__ bprev, double Nprev,
    short* __restrict__ out, double* __restrict__ statsOut, int B, int VB,
    const float* __restrict__ wown,
    const float* __restrict__ pw2, const float* __restrict__ pw3,
    const float* __restrict__ pw4, const float* __restrict__ pw5,
    int* __restrict__ owp2, int* __restrict__ owp3,
    int* __restrict__ owp4, int* __restrict__ owp5)
{
    constexpr int KW   = (K + 3) / 4;
    constexpr int NE   = P + 2 * KW - 1;
    constexpr int ND   = (2 * (NE - 1) + 3) / 4 + 2;
    constexpr int LO_P = (LOUT + P - 1) / P;
    constexpr int GROUPS = R * LO_P;

    __shared__ __align__(16) signed char smem[R * CIN * LINP + 32];
    __shared__ float ts[CIN], tb[CIN];
    __shared__ float red[4][2 * COUT];
    __shared__ int lwq[IN_FLOAT ? (COUT * CIN * KW) : 1];

    const int tid = threadIdx.x;
    const int bid = blockIdx.x;
    const int lane = tid & 63, wid = tid >> 6;

    if constexpr (IN_FLOAT) {
        for (int i = tid; i < COUT * CIN * KW; i += 256) {
            int j = i % KW, cc = i / KW;
            unsigned rr = 0;
            for (int u = 0; u < 4; u++) {
                int k = 4 * j + u;
                int bv = (k < K) ? (qw8i(wown[cc * K + k]) & 0xff) : 0;
                rr |= (unsigned)bv << (8 * u);
            }
            lwq[i] = (int)rr;
        }
        if (bid == 0) {
            pack_layer(pw2, owp2, 3, 5, 5, tid);
            pack_layer(pw3, owp3, 5, 10, 4, tid);
            pack_layer(pw4, owp4, 10, 20, 4, tid);
            pack_layer(pw5, owp5, 20, 20, 4, tid);
        }
    } else {
        // trivial BN bridge: 16 fp64 loads + fold, CIN threads (R0-proven)
        if (tid < CIN) {
            double S = 0.0, Q = 0.0;
#pragma unroll
            for (int s = 0; s < 8; s++) {
                S += statsIn[s * (2 * CIN) + 2 * tid];
                Q += statsIn[s * (2 * CIN) + 2 * tid + 1];
            }
            double mean = S / Nprev;
            double var  = Q / Nprev - mean * mean;
            double inv  = 1.0 / sqrt(var + 1e-5);
            double sc   = (double)gprev[tid] * inv;
            ts[tid] = (float)sc * 0.015625f;     // fold /64 of int16 storage
            tb[tid] = (float)((double)bprev[tid] - mean * sc);
        }
    }
    __syncthreads();

    // per-thread stat accumulators carried across the whole vb loop
    float tsum[COUT], tsq[COUT];
#pragma unroll
    for (int c = 0; c < COUT; c++) { tsum[c] = 0.f; tsq[c] = 0.f; }

#pragma unroll 1
    for (int vb = bid; vb < VB; vb += gridDim.x) {
        const int r0   = vb * R;
        const int rcnt = min(R, B - r0);

        // ---- stage: global -> quantized int8 LDS (4-deep prefetch) ----
        if constexpr (IN_FLOAT) {
            constexpr int CH = LIN / 2;
            const float2* gp = (const float2*)in_;
            const int total = rcnt * CH;
#pragma unroll 1
            for (int base = 0; base < total; base += 1024) {
                float2 v[4];
#pragma unroll
                for (int u = 0; u < 4; u++) {
                    int c = base + u * 256 + tid;
                    if (c < total) v[u] = gp[(size_t)r0 * CH + c];
                }
#pragma unroll
                for (int u = 0; u < 4; u++) {
                    int c = base + u * 256 + tid;
                    if (c < total) {
                        int r = c / CH, rem = c - r * CH;
                        int b0 = q8i(v[u].x, 1.f, 0.f) & 0xff;
                        int b1 = q8i(v[u].y, 1.f, 0.f) & 0xff;
                        *(unsigned short*)(smem + r * LINP + rem * 2) =
                            (unsigned short)(b0 | (b1 << 8));
                    }
                }
            }
        } else {
            constexpr int CH  = CIN * LINP / 8;
            constexpr int CHC = LINP / 8;
            const int4* gp = (const int4*)((const short*)in_ + (size_t)r0 * CIN * LINP);
            const int total = rcnt * CH;
#pragma unroll 1
            for (int base = 0; base < total; base += 1024) {
                int4 v[4];
#pragma unroll
                for (int u = 0; u < 4; u++) {
                    int c = base + u * 256 + tid;
                    if (c < total) v[u] = gp[c];
                }
#pragma unroll
                for (int u = 0; u < 4; u++) {
                    int c = base + u * 256 + tid;
                    if (c < total) {
                        int rem = c % CH;
                        int ci = rem / CHC;
                        float a = ts[ci], bo = tb[ci];
                        int vs[4] = { v[u].x, v[u].y, v[u].z, v[u].w };
                        unsigned pk[2];
#pragma unroll
                        for (int w8 = 0; w8 < 2; w8++) {
                            unsigned pp = 0;
#pragma unroll
                            for (int j = 0; j < 2; j++) {
                                int word = vs[w8 * 2 + j];
                                int b0 = q8i((float)(short)(word & 0xffff), a, bo) & 0xff;
                                int b1 = q8i((float)(short)(word >> 16),    a, bo) & 0xff;
                                pp |= (unsigned)(b0 | (b1 << 8)) << (16 * j);
                            }
                            pk[w8] = pp;
                        }
                        ((uint2*)smem)[c] = make_uint2(pk[0], pk[1]);
                    }
                }
            }
        }
        __syncthreads();

        // ---- compute core (accumulates into block-lifetime tsum/tsq) ----
#pragma unroll 1
        for (int g = tid; g < GROUPS; g += 256) {
            int r = g / LO_P;
            if (r >= rcnt) continue;
            int l0   = (g - r * LO_P) * P;
            int pact = min(P, LOUT - l0);

            int acc[COUT][P];
#pragma unroll
            for (int co = 0; co < COUT; co++)
#pragma unroll
                for (int p = 0; p < P; p++) acc[co][p] = 0;

            const int ibase = r * CIN * LINP + 2 * l0;
            const int sh    = (P % 2 == 0) ? 0 : (ibase & 3);

            for (int ci = 0; ci < CIN; ci++) {
                const int* sp = (const int*)smem + ((ci * LINP + (ibase & ~3)) >> 2);
                int d[ND];
#pragma unroll
                for (int j = 0; j < ND; j++) d[j] = sp[j];
                int e[NE];
#pragma unroll
                for (int i = 0; i < NE; i++) {
                    int off = sh + 2 * i;
                    e[i] = (int)alignpair((unsigned)d[off / 4 + 1], (unsigned)d[off / 4], (off & 3) * 8);
                }
#pragma unroll
                for (int co = 0; co < COUT; co++) {
#pragma unroll
                    for (int j = 0; j < KW; j++) {
                        int wv;
                        if constexpr (IN_FLOAT) wv = lwq[(co * CIN + ci) * KW + j];
                        else                    wv = wqi[(co * CIN + ci) * KW + j];
#pragma unroll
                        for (int p = 0; p < P; p++)
                            acc[co][p] = dot4(e[p + 2 * j], wv, acc[co][p]);
                    }
                }
            }

            const size_t ob = (size_t)(r0 + r) * COUT * LOUTP + l0;
#pragma unroll
            for (int co = 0; co < COUT; co++) {
                if (pact == P) {
                    short tmp[P];
#pragma unroll
                    for (int p = 0; p < P; p++) {
                        tmp[p] = (short)acc[co][p];
                        float v = (float)acc[co][p] * 0.015625f;
                        tsum[co] += v;
                        tsq[co]   = fmaf(v, v, tsq[co]);
                    }
                    short* op = &out[ob + (size_t)co * LOUTP];
                    if constexpr (P == 1) {
                        op[0] = tmp[0];
                    } else if constexpr (P == 2) {
                        *(short2*)op = make_short2(tmp[0], tmp[1]);
                    } else if constexpr (P == 4) {
                        *(short4*)op = make_short4(tmp[0], tmp[1], tmp[2], tmp[3]);
                    } else if constexpr (P == 8) {
                        *(short4*)op       = make_short4(tmp[0], tmp[1], tmp[2], tmp[3]);
                        *(short4*)(op + 4) = make_short4(tmp[4], tmp[5], tmp[6], tmp[7]);
                    }
                } else {
#pragma unroll
                    for (int p = 0; p < P; p++) {
                        if (p < pact) {
                            int k = acc[co][p];
                            out[ob + (size_t)co * LOUTP + p] = (short)k;
                            float v = (float)k * 0.015625f;
                            tsum[co] += v;
                            tsq[co]   = fmaf(v, v, tsq[co]);
                        }
                    }
                }
            }
        }
        __syncthreads();   // protect smem for next vb's staging
    }

    // ---- ONE stat reduction + slot atomic per block ----
#pragma unroll
    for (int co = 0; co < COUT; co++) {
        float s = tsum[co], q = tsq[co];
        for (int off = 32; off > 0; off >>= 1) {
            s += __shfl_down(s, off, 64);
            q += __shfl_down(q, off, 64);
        }
        if (lane == 0) { red[wid][2 * co] = s; red[wid][2 * co + 1] = q; }
    }
    __syncthreads();
    if (tid < 2 * COUT) {
        float v = red[0][tid] + red[1][tid] + red[2][tid] + red[3][tid];
        atomAddF64(&statsOut[(size_t)(bid & 7) * (2 * COUT) + tid], (double)v);
    }
}

// ---- distinctly-named per-layer wrappers (rocprof attribution) ----
__global__ __launch_bounds__(256) void k_conv1(
    const float* x, short* y1, double* sl1, int B, int VB,
    const float* w1, const float* w2, const float* w3, const float* w4,
    const float* w5, int* wp2, int* wp3, int* wp4, int* wp5)
{
    conv_phase<1, 3, 6, 1252, 623, 624, 8, 3, true, 1250>(
        x, nullptr, nullptr, nullptr, nullptr, 0.0, y1, sl1, B, VB,
        w1, w2, w3, w4, w5, wp2, wp3, wp4, wp5);
}
__global__ __launch_bounds__(256) void k_conv2(
    const short* in_, const int* wq, const double* sIn,
    const float* g, const float* b, short* out, double* sOut, int B, int VB)
{
    conv_phase<3, 5, 5, 624, 310, 312, 4, 4, false>(
        in_, wq, sIn, g, b, 8192.0 * 623.0, out, sOut, B, VB,
        nullptr, nullptr, nullptr, nullptr, nullptr, nullptr, nullptr, nullptr, nullptr);
}
__global__ __launch_bounds__(256) void k_conv3(
    const short* in_, const int* wq, const double* sIn,
    const float* g, const float* b, short* out, double* sOut, int B, int VB)
{
    conv_phase<5, 10, 4, 312, 154, 160, 2, 4, false>(
        in_, wq, sIn, g, b, 8192.0 * 310.0, out, sOut, B, VB,
        nullptr, nullptr, nullptr, nullptr, nullptr, nullptr, nullptr, nullptr, nullptr);
}
__global__ __launch_bounds__(256) void k_conv4(
    const short* in_, const int* wq, const double* sIn,
    const float* g, const float* b, short* out, double* sOut, int B, int VB)
{
    conv_phase<10, 20, 4, 160, 76, 80, 1, 4, false>(
        in_, wq, sIn, g, b, 8192.0 * 154.0, out, sOut, B, VB,
        nullptr, nullptr, nullptr, nullptr, nullptr, nullptr, nullptr, nullptr, nullptr);
}
__global__ __launch_bounds__(256) void k_conv5(
    const short* in_, const int* wq, const double* sIn,
    const float* g, const float* b, short* out, double* sOut, int B, int VB)
{
    conv_phase<20, 20, 4, 80, 37, 40, 1, 8, false>(
        in_, wq, sIn, g, b, 8192.0 * 76.0, out, sOut, B, VB,
        nullptr, nullptr, nullptr, nullptr, nullptr, nullptr, nullptr, nullptr, nullptr);
}

// ---------------------------------------------------------------------------
// FC1 + last-block FC2 tail, ZERO fences (R4's merge minus its threadfence
// cost). Coherence by construction:
//   - z1 written via AGENT-scope relaxed atomic stores (write-through to the
//     coherent point; no fence needed for device visibility);
//   - sl6 via device-scope f64 atomicAdd (coherent by definition);
//   - __syncthreads() before the done-counter bump emits s_waitcnt vmcnt(0)
//     (compiler-guaranteed barrier semantics) -> all stores retired BEFORE
//     the counter increment is visible;
//   - last block (old == grid-1) reads z1 / sl6 via AGENT atomic loads.
// FC1 math, z1 values, sl6 sums and the FC2 tail math are R10-verbatim ->
// bit-identical output. zbuf lives in global ws (z2): LDS is taken by wq.
// ---------------------------------------------------------------------------
__global__ __launch_bounds__(256) void k_fc1_fc2(
    const short* __restrict__ y5, const float* __restrict__ fw1,
    const double* __restrict__ statsIn,
    const float* __restrict__ g5, const float* __restrict__ b5,
    float* __restrict__ z1, double* __restrict__ statsOut,
    const float* __restrict__ fw2,
    const float* __restrict__ g6, const float* __restrict__ b6,
    const float* __restrict__ g7, const float* __restrict__ b7,
    float* __restrict__ z2, float* __restrict__ outp,
    unsigned* __restrict__ doneCtr, int B)
{
    __shared__ float wq[7400];
    __shared__ float ts[20], tb[20];
    __shared__ float red[4][20];
    __shared__ float ts7[10], tb7[10], wq2[20];
    __shared__ float fr[4][4];
    __shared__ float tr8[4];
    __shared__ unsigned lastFlag;

    const int tid = threadIdx.x;
    const int bid = blockIdx.x;
    const int lane = tid & 63, wid = tid >> 6;

    for (int i = tid; i < 7400; i += 256) wq[i] = qwt(fw1[i]);
    if (tid < 20) {
        double S = 0.0, Q = 0.0;
#pragma unroll
        for (int s = 0; s < 8; s++) {
            S += statsIn[s * 40 + 2 * tid];
            Q += statsIn[s * 40 + 2 * tid + 1];
        }
        double N = 8192.0 * 37.0;
        double mean = S / N;
        double var  = Q / N - mean * mean;
        double inv  = 1.0 / sqrt(var + 1e-5);
        double sc   = (double)g5[tid] * inv;
        ts[tid] = (float)sc;                 // x already carries 1/64
        tb[tid] = (float)((double)b5[tid] - mean * sc);
    }
    __syncthreads();

    float tsum[10], tsq[10];
#pragma unroll
    for (int j = 0; j < 10; j++) { tsum[j] = 0.f; tsq[j] = 0.f; }

#pragma unroll 1
    for (int r = bid * 4 + wid; r < B; r += gridDim.x * 4) {
        const short* xr = y5 + (size_t)r * 800;   // 20ch x 40 padded
        float acc[10];
#pragma unroll
        for (int j = 0; j < 10; j++) acc[j] = 0.f;
#pragma unroll 1
        for (int f = lane; f < 740; f += 64) {
            int c = f / 37, pos = f - c * 37;
            float x = qact((float)xr[c * 40 + pos] * 0.015625f, ts[c], tb[c]);
#pragma unroll
            for (int j = 0; j < 10; j++) acc[j] = fmaf(x, wq[j * 740 + f], acc[j]);
        }
#pragma unroll
        for (int j = 0; j < 10; j++) {
            float v = acc[j];
            for (int off = 1; off < 64; off <<= 1) v += __shfl_xor(v, off, 64);
            tsum[j] += v; tsq[j] = fmaf(v, v, tsq[j]);
            if (lane == j)
                __hip_atomic_store(&z1[(size_t)r * 10 + j], v,
                                   __ATOMIC_RELAXED, __HIP_MEMORY_SCOPE_AGENT);
        }
    }
    if (lane == 0) {
#pragma unroll
        for (int j = 0; j < 10; j++) { red[wid][2 * j] = tsum[j]; red[wid][2 * j + 1] = tsq[j]; }
    }
    __syncthreads();
    if (tid < 20) {
        float v = red[0][tid] + red[1][tid] + red[2][tid] + red[3][tid];
        atomAddF64(&statsOut[(size_t)(bid & 7) * 20 + tid], (double)v);
    }

    // ---- last-block detection (vmcnt(0) drain via barrier; NO fence) ----
    __syncthreads();
    if (tid == 0) {
        unsigned old = atomicAdd(doneCtr, 1u);
        lastFlag = (old == gridDim.x - 1) ? 1u : 0u;
    }
    __syncthreads();
    if (!lastFlag) return;

    // ================= FC2 tail (R10 k_fc2 verbatim math) =================
    if (tid < 20) wq2[tid] = qwt(fw2[tid]);
    if (tid < 10) {
        double S = 0.0, Q = 0.0;
#pragma unroll
        for (int s = 0; s < 8; s++) {
            S += aldD(&statsOut[s * 20 + 2 * tid]);
            Q += aldD(&statsOut[s * 20 + 2 * tid + 1]);
        }
        double N = 8192.0;
        double mean = S / N;
        double var  = Q / N - mean * mean;
        double inv  = 1.0 / sqrt(var + 1e-5);
        double sc   = (double)g6[tid] * inv;
        ts7[tid] = (float)sc;
        tb7[tid] = (float)((double)b6[tid] - mean * sc);
    }
    __syncthreads();

    float s0 = 0.f, q0 = 0.f, s1 = 0.f, q1 = 0.f;
#pragma unroll 1
    for (int r = tid; r < B; r += 512) {
        const int r2 = r + 256;
        float a0 = 0.f, a1 = 0.f, c0 = 0.f, c1 = 0.f;
#pragma unroll
        for (int i = 0; i < 10; i++) {
            float zv = __hip_atomic_load(&z1[(size_t)r * 10 + i],
                                         __ATOMIC_RELAXED, __HIP_MEMORY_SCOPE_AGENT);
            float xA = qact(zv, ts7[i], tb7[i]);
            a0 = fmaf(xA, wq2[i], a0);
            a1 = fmaf(xA, wq2[10 + i], a1);
        }
#pragma unroll
        for (int i = 0; i < 10; i++) {
            float zv = __hip_atomic_load(&z1[(size_t)r2 * 10 + i],
                                         __ATOMIC_RELAXED, __HIP_MEMORY_SCOPE_AGENT);
            float xB = qact(zv, ts7[i], tb7[i]);
            c0 = fmaf(xB, wq2[i], c0);
            c1 = fmaf(xB, wq2[10 + i], c1);
        }
        z2[r * 2]      = a0;
        z2[r * 2 + 1]  = a1;
        z2[r2 * 2]     = c0;
        z2[r2 * 2 + 1] = c1;
        // stat-add order: r first, then r+256 (matches original sequence)
        s0 += a0; q0 = fmaf(a0, a0, q0);
        s1 += a1; q1 = fmaf(a1, a1, q1);
        s0 += c0; q0 = fmaf(c0, c0, q0);
        s1 += c1; q1 = fmaf(c1, c1, q1);
    }
    for (int off = 32; off > 0; off >>= 1) {
        s0 += __shfl_down(s0, off, 64); q0 += __shfl_down(q0, off, 64);
        s1 += __shfl_down(s1, off, 64); q1 += __shfl_down(q1, off, 64);
    }
    if (lane == 0) { fr[wid][0] = s0; fr[wid][1] = q0; fr[wid][2] = s1; fr[wid][3] = q1; }
    __syncthreads();
    if (tid < 2) {
        double S = 0.0, Q = 0.0;
        for (int w = 0; w < 4; w++) { S += (double)fr[w][2 * tid]; Q += (double)fr[w][2 * tid + 1]; }
        double N = (double)B;
        double mean = S / N;
        double var  = Q / N - mean * mean;
        double inv  = 1.0 / sqrt(var + 1e-5);
        double sc   = (double)g7[tid] * inv;
        tr8[tid]     = (float)sc;
        tr8[2 + tid] = (float)((double)b7[tid] - mean * sc);
    }
    __syncthreads();
    for (int i = tid; i < 2 * B; i += 256) {
        int c = i & 1;
        outp[i] = fmaf(z2[i], tr8[c], tr8[2 + c]);
    }
}

// ---------------------------------------------------------------------------
extern "C" void kernel_launch(void* const* d_in, const int* in_sizes, int n_in,
                              void* d_out, int out_size, void* d_ws, size_t ws_size,
                              hipStream_t stream)
{
    const float* x   = (const float*)d_in[0];
    const float* w1  = (const float*)d_in[1];
    const float* w2  = (const float*)d_in[2];
    const float* w3  = (const float*)d_in[3];
    const float* w4  = (const float*)d_in[4];
    const float* w5  = (const float*)d_in[5];
    const float* fw1 = (const float*)d_in[6];
    const float* fw2 = (const float*)d_in[7];
    const float *g[7], *bb[7];
    for (int i = 0; i < 7; i++) { g[i] = (const float*)d_in[8 + 2 * i]; bb[i] = (const float*)d_in[9 + 2 * i]; }

    char* ws = (char*)d_ws;
    size_t off = 0;
    auto alloc = [&](size_t bytes) -> void* {
        void* q = ws + off;
        off += (bytes + 255) & ~(size_t)255;
        return q;
    };
    short* y1 = (short*)alloc((size_t)8192 * 3 * 624 * 2);
    short* y2 = (short*)alloc((size_t)8192 * 5 * 312 * 2);
    short* y3 = (short*)alloc((size_t)8192 * 10 * 160 * 2);
    short* y4 = (short*)alloc((size_t)8192 * 20 * 80 * 2);
    short* y5 = (short*)alloc((size_t)8192 * 20 * 40 * 2);
    float* z1 = (float*)alloc((size_t)81920 * 4);
    float* z2 = (float*)alloc((size_t)8192 * 2 * 4);
    int*   wp2 = (int*)alloc(256);  int* wp3 = (int*)alloc(256);
    int*   wp4 = (int*)alloc(1024); int* wp5 = (int*)alloc(2048);
    // fp64 stat slots (1088 doubles) + done counter, single memset region
    double* slots = (double*)alloc((size_t)1088 * 8 + 256);
    double* sl1 = slots;              // conv1: 8 x 6
    double* sl2 = sl1 + 8 * 6;        // conv2: 8 x 10
    double* sl3 = sl2 + 8 * 10;       // conv3: 8 x 20
    double* sl4 = sl3 + 8 * 20;       // conv4: 8 x 40
    double* sl5 = sl4 + 8 * 40;       // conv5: 8 x 40
    double* sl6 = sl5 + 8 * 40;       // fc1:   8 x 20
    unsigned* doneCtr = (unsigned*)(sl6 + 8 * 20);

    const int B = 8192;

    hipMemsetAsync(slots, 0, (size_t)1088 * 8 + 256, stream);

    k_conv1<<<1024, 256, 0, stream>>>(x, y1, sl1, B, 2731,
                                      w1, w2, w3, w4, w5, wp2, wp3, wp4, wp5);
    k_conv2<<<1024, 256, 0, stream>>>(y1, wp2, sl1, g[0], bb[0], y2, sl2, B, 2048);
    k_conv3<<<1024, 256, 0, stream>>>(y2, wp3, sl2, g[1], bb[1], y3, sl3, B, 2048);
    k_conv4<<<1024, 256, 0, stream>>>(y3, wp4, sl3, g[2], bb[2], y4, sl4, B, 2048);
    k_conv5<<<1024, 256, 0, stream>>>(y4, wp5, sl4, g[3], bb[3], y5, sl5, B, 1024);
    k_fc1_fc2<<<2048, 256, 0, stream>>>(y5, fw1, sl5, g[4], bb[4], z1, sl6,
                                        fw2, g[5], bb[5], g[6], bb[6],
                                        z2, (float*)d_out, doneCtr, B);
}

// Round 12
// 273.859 us; speedup vs baseline: 1.1438x; 1.1438x over previous
//
#include <hip/hip_runtime.h>

#define DEV __device__ __forceinline__

// ---- quantizer helpers (exact, round-half-even matches jnp.round) ----
DEV float qwt(float w) {
    float y = fminf(fmaxf(w, -1.0f), 0.875f);
    return rintf(y * 8.0f) * 0.125f;
}
DEV int qw8i(float w) {                       // weight -> int in [-8,7]
    float y = fminf(fmaxf(w, -1.0f), 0.875f);
    return (int)rintf(y * 8.0f);
}
DEV int q8i(float x, float a, float b) {      // act -> int in [-8,7]
    float y = fmaf(x, a, b);
    y = fminf(fmaxf(y, -1.0f), 0.875f);
    return (int)rintf(y * 8.0f);
}
DEV float qact(float x, float a, float b) {
    float y = fmaf(x, a, b);
    y = fminf(fmaxf(y, -1.0f), 0.875f);
    return rintf(y * 8.0f) * 0.125f;
}

DEV int dot4(int a, int b, int c) {
#if __has_builtin(__builtin_amdgcn_sdot4)
    return __builtin_amdgcn_sdot4(a, b, c, false);
#else
    c += (int)(signed char)(a)       * (int)(signed char)(b);
    c += (int)(signed char)(a >> 8)  * (int)(signed char)(b >> 8);
    c += (int)(signed char)(a >> 16) * (int)(signed char)(b >> 16);
    c += (int)(signed char)(a >> 24) * (int)(signed char)(b >> 24);
    return c;
#endif
}
DEV unsigned alignpair(unsigned hi, unsigned lo, int bits) {
#if __has_builtin(__builtin_amdgcn_alignbit)
    return __builtin_amdgcn_alignbit(hi, lo, bits);
#else
    return bits ? ((lo >> bits) | (hi << (32 - bits))) : lo;
#endif
}

DEV void atomAddF64(double* p, double v) { atomicAdd(p, v); }

// pack float OIHW weights -> int8x4 dwords (value*8), zero-padded past K
DEV void pack_layer(const float* w, int* o, int CIN, int COUT, int K, int t) {
    int KW = (K + 3) / 4;
    for (int i = t; i < COUT * CIN * KW; i += 256) {
        int j = i % KW, cc = i / KW;
        unsigned r = 0;
        for (int u = 0; u < 4; u++) {
            int k = 4 * j + u;
            int b = (k < K) ? (qw8i(w[cc * K + k]) & 0xff) : 0;
            r |= (unsigned)b << (8 * u);
        }
        o[i] = (int)r;
    }
}

// pack fc1 weights (10 x 740) -> int8x4 dwords, f padded to 768.
// o[j*192 + d] byte u = qw8i(fw1[j*740 + 4d+u]) for 4d+u < 740, else 0.
DEV void pack_fc1(const float* fw1, int* o, int t) {
    for (int i = t; i < 1920; i += 256) {
        int j = i / 192, d = i - j * 192;
        unsigned r = 0;
        for (int u = 0; u < 4; u++) {
            int f = 4 * d + u;
            int b = (f < 740) ? (qw8i(fw1[j * 740 + f]) & 0xff) : 0;
            r |= (unsigned)b << (8 * u);
        }
        o[i] = (int)r;
    }
}

// ---------------------------------------------------------------------------
// int8/dot4 1-D strided conv (stride 2, VALID). R10-proven: vb-loop grid
// 1024, 4-deep staging prefetch, block-lifetime tsum/tsq with ONE butterfly
// + slot atomic per block (slot bid&7).
// ---------------------------------------------------------------------------
template<int CIN,int COUT,int K,int LINP,int LOUT,int LOUTP,int P,int R,bool IN_FLOAT,int LIN=0>
DEV void conv_phase(
    const void* __restrict__ in_, const int* __restrict__ wqi,
    const double* __restrict__ statsIn,
    const float* __restrict__ gprev, const float* __restrict__ bprev, double Nprev,
    short* __restrict__ out, double* __restrict__ statsOut, int B, int VB,
    const float* __restrict__ wown,
    const float* __restrict__ pw2, const float* __restrict__ pw3,
    const float* __restrict__ pw4, const float* __restrict__ pw5,
    int* __restrict__ owp2, int* __restrict__ owp3,
    int* __restrict__ owp4, int* __restrict__ owp5)
{
    constexpr int KW   = (K + 3) / 4;
    constexpr int NE   = P + 2 * KW - 1;
    constexpr int ND   = (2 * (NE - 1) + 3) / 4 + 2;
    constexpr int LO_P = (LOUT + P - 1) / P;
    constexpr int GROUPS = R * LO_P;

    __shared__ __align__(16) signed char smem[R * CIN * LINP + 32];
    __shared__ float ts[CIN], tb[CIN];
    __shared__ float red[4][2 * COUT];
    __shared__ int lwq[IN_FLOAT ? (COUT * CIN * KW) : 1];

    const int tid = threadIdx.x;
    const int bid = blockIdx.x;
    const int lane = tid & 63, wid = tid >> 6;

    if constexpr (IN_FLOAT) {
        for (int i = tid; i < COUT * CIN * KW; i += 256) {
            int j = i % KW, cc = i / KW;
            unsigned rr = 0;
            for (int u = 0; u < 4; u++) {
                int k = 4 * j + u;
                int bv = (k < K) ? (qw8i(wown[cc * K + k]) & 0xff) : 0;
                rr |= (unsigned)bv << (8 * u);
            }
            lwq[i] = (int)rr;
        }
        if (bid == 0) {
            pack_layer(pw2, owp2, 3, 5, 5, tid);
            pack_layer(pw3, owp3, 5, 10, 4, tid);
            pack_layer(pw4, owp4, 10, 20, 4, tid);
            pack_layer(pw5, owp5, 20, 20, 4, tid);
        }
    } else {
        // trivial BN bridge: 16 fp64 loads + fold, CIN threads (R0-proven)
        if (tid < CIN) {
            double S = 0.0, Q = 0.0;
#pragma unroll
            for (int s = 0; s < 8; s++) {
                S += statsIn[s * (2 * CIN) + 2 * tid];
                Q += statsIn[s * (2 * CIN) + 2 * tid + 1];
            }
            double mean = S / Nprev;
            double var  = Q / Nprev - mean * mean;
            double inv  = 1.0 / sqrt(var + 1e-5);
            double sc   = (double)gprev[tid] * inv;
            ts[tid] = (float)sc * 0.015625f;     // fold /64 of int16 storage
            tb[tid] = (float)((double)bprev[tid] - mean * sc);
        }
    }
    __syncthreads();

    // per-thread stat accumulators carried across the whole vb loop
    float tsum[COUT], tsq[COUT];
#pragma unroll
    for (int c = 0; c < COUT; c++) { tsum[c] = 0.f; tsq[c] = 0.f; }

#pragma unroll 1
    for (int vb = bid; vb < VB; vb += gridDim.x) {
        const int r0   = vb * R;
        const int rcnt = min(R, B - r0);

        // ---- stage: global -> quantized int8 LDS (4-deep prefetch) ----
        if constexpr (IN_FLOAT) {
            constexpr int CH = LIN / 2;
            const float2* gp = (const float2*)in_;
            const int total = rcnt * CH;
#pragma unroll 1
            for (int base = 0; base < total; base += 1024) {
                float2 v[4];
#pragma unroll
                for (int u = 0; u < 4; u++) {
                    int c = base + u * 256 + tid;
                    if (c < total) v[u] = gp[(size_t)r0 * CH + c];
                }
#pragma unroll
                for (int u = 0; u < 4; u++) {
                    int c = base + u * 256 + tid;
                    if (c < total) {
                        int r = c / CH, rem = c - r * CH;
                        int b0 = q8i(v[u].x, 1.f, 0.f) & 0xff;
                        int b1 = q8i(v[u].y, 1.f, 0.f) & 0xff;
                        *(unsigned short*)(smem + r * LINP + rem * 2) =
                            (unsigned short)(b0 | (b1 << 8));
                    }
                }
            }
        } else {
            constexpr int CH  = CIN * LINP / 8;
            constexpr int CHC = LINP / 8;
            const int4* gp = (const int4*)((const short*)in_ + (size_t)r0 * CIN * LINP);
            const int total = rcnt * CH;
#pragma unroll 1
            for (int base = 0; base < total; base += 1024) {
                int4 v[4];
#pragma unroll
                for (int u = 0; u < 4; u++) {
                    int c = base + u * 256 + tid;
                    if (c < total) v[u] = gp[c];
                }
#pragma unroll
                for (int u = 0; u < 4; u++) {
                    int c = base + u * 256 + tid;
                    if (c < total) {
                        int rem = c % CH;
                        int ci = rem / CHC;
                        float a = ts[ci], bo = tb[ci];
                        int vs[4] = { v[u].x, v[u].y, v[u].z, v[u].w };
                        unsigned pk[2];
#pragma unroll
                        for (int w8 = 0; w8 < 2; w8++) {
                            unsigned pp = 0;
#pragma unroll
                            for (int j = 0; j < 2; j++) {
                                int word = vs[w8 * 2 + j];
                                int b0 = q8i((float)(short)(word & 0xffff), a, bo) & 0xff;
                                int b1 = q8i((float)(short)(word >> 16),    a, bo) & 0xff;
                                pp |= (unsigned)(b0 | (b1 << 8)) << (16 * j);
                            }
                            pk[w8] = pp;
                        }
                        ((uint2*)smem)[c] = make_uint2(pk[0], pk[1]);
                    }
                }
            }
        }
        __syncthreads();

        // ---- compute core (accumulates into block-lifetime tsum/tsq) ----
#pragma unroll 1
        for (int g = tid; g < GROUPS; g += 256) {
            int r = g / LO_P;
            if (r >= rcnt) continue;
            int l0   = (g - r * LO_P) * P;
            int pact = min(P, LOUT - l0);

            int acc[COUT][P];
#pragma unroll
            for (int co = 0; co < COUT; co++)
#pragma unroll
                for (int p = 0; p < P; p++) acc[co][p] = 0;

            const int ibase = r * CIN * LINP + 2 * l0;
            const int sh    = (P % 2 == 0) ? 0 : (ibase & 3);

            for (int ci = 0; ci < CIN; ci++) {
                const int* sp = (const int*)smem + ((ci * LINP + (ibase & ~3)) >> 2);
                int d[ND];
#pragma unroll
                for (int j = 0; j < ND; j++) d[j] = sp[j];
                int e[NE];
#pragma unroll
                for (int i = 0; i < NE; i++) {
                    int off = sh + 2 * i;
                    e[i] = (int)alignpair((unsigned)d[off / 4 + 1], (unsigned)d[off / 4], (off & 3) * 8);
                }
#pragma unroll
                for (int co = 0; co < COUT; co++) {
#pragma unroll
                    for (int j = 0; j < KW; j++) {
                        int wv;
                        if constexpr (IN_FLOAT) wv = lwq[(co * CIN + ci) * KW + j];
                        else                    wv = wqi[(co * CIN + ci) * KW + j];
#pragma unroll
                        for (int p = 0; p < P; p++)
                            acc[co][p] = dot4(e[p + 2 * j], wv, acc[co][p]);
                    }
                }
            }

            const size_t ob = (size_t)(r0 + r) * COUT * LOUTP + l0;
#pragma unroll
            for (int co = 0; co < COUT; co++) {
                if (pact == P) {
                    short tmp[P];
#pragma unroll
                    for (int p = 0; p < P; p++) {
                        tmp[p] = (short)acc[co][p];
                        float v = (float)acc[co][p] * 0.015625f;
                        tsum[co] += v;
                        tsq[co]   = fmaf(v, v, tsq[co]);
                    }
                    short* op = &out[ob + (size_t)co * LOUTP];
                    if constexpr (P == 1) {
                        op[0] = tmp[0];
                    } else if constexpr (P == 2) {
                        *(short2*)op = make_short2(tmp[0], tmp[1]);
                    } else if constexpr (P == 4) {
                        *(short4*)op = make_short4(tmp[0], tmp[1], tmp[2], tmp[3]);
                    } else if constexpr (P == 8) {
                        *(short4*)op       = make_short4(tmp[0], tmp[1], tmp[2], tmp[3]);
                        *(short4*)(op + 4) = make_short4(tmp[4], tmp[5], tmp[6], tmp[7]);
                    }
                } else {
#pragma unroll
                    for (int p = 0; p < P; p++) {
                        if (p < pact) {
                            int k = acc[co][p];
                            out[ob + (size_t)co * LOUTP + p] = (short)k;
                            float v = (float)k * 0.015625f;
                            tsum[co] += v;
                            tsq[co]   = fmaf(v, v, tsq[co]);
                        }
                    }
                }
            }
        }
        __syncthreads();   // protect smem for next vb's staging
    }

    // ---- ONE stat reduction + slot atomic per block ----
#pragma unroll
    for (int co = 0; co < COUT; co++) {
        float s = tsum[co], q = tsq[co];
        for (int off = 32; off > 0; off >>= 1) {
            s += __shfl_down(s, off, 64);
            q += __shfl_down(q, off, 64);
        }
        if (lane == 0) { red[wid][2 * co] = s; red[wid][2 * co + 1] = q; }
    }
    __syncthreads();
    if (tid < 2 * COUT) {
        float v = red[0][tid] + red[1][tid] + red[2][tid] + red[3][tid];
        atomAddF64(&statsOut[(size_t)(bid & 7) * (2 * COUT) + tid], (double)v);
    }
}

// ---- distinctly-named per-layer wrappers (rocprof attribution) ----
__global__ __launch_bounds__(256) void k_conv1(
    const float* x, short* y1, double* sl1, int B, int VB,
    const float* w1, const float* w2, const float* w3, const float* w4,
    const float* w5, int* wp2, int* wp3, int* wp4, int* wp5,
    const float* fw1, int* wp6)
{
    if (blockIdx.x == 0) pack_fc1(fw1, wp6, threadIdx.x);
    conv_phase<1, 3, 6, 1252, 623, 624, 8, 3, true, 1250>(
        x, nullptr, nullptr, nullptr, nullptr, 0.0, y1, sl1, B, VB,
        w1, w2, w3, w4, w5, wp2, wp3, wp4, wp5);
}
__global__ __launch_bounds__(256) void k_conv2(
    const short* in_, const int* wq, const double* sIn,
    const float* g, const float* b, short* out, double* sOut, int B, int VB)
{
    conv_phase<3, 5, 5, 624, 310, 312, 4, 4, false>(
        in_, wq, sIn, g, b, 8192.0 * 623.0, out, sOut, B, VB,
        nullptr, nullptr, nullptr, nullptr, nullptr, nullptr, nullptr, nullptr, nullptr);
}
__global__ __launch_bounds__(256) void k_conv3(
    const short* in_, const int* wq, const double* sIn,
    const float* g, const float* b, short* out, double* sOut, int B, int VB)
{
    conv_phase<5, 10, 4, 312, 154, 160, 2, 4, false>(
        in_, wq, sIn, g, b, 8192.0 * 310.0, out, sOut, B, VB,
        nullptr, nullptr, nullptr, nullptr, nullptr, nullptr, nullptr, nullptr, nullptr);
}
__global__ __launch_bounds__(256) void k_conv4(
    const short* in_, const int* wq, const double* sIn,
    const float* g, const float* b, short* out, double* sOut, int B, int VB)
{
    conv_phase<10, 20, 4, 160, 76, 80, 1, 4, false>(
        in_, wq, sIn, g, b, 8192.0 * 154.0, out, sOut, B, VB,
        nullptr, nullptr, nullptr, nullptr, nullptr, nullptr, nullptr, nullptr, nullptr);
}
__global__ __launch_bounds__(256) void k_conv5(
    const short* in_, const int* wq, const double* sIn,
    const float* g, const float* b, short* out, double* sOut, int B, int VB)
{
    conv_phase<20, 20, 4, 80, 37, 40, 1, 8, false>(
        in_, wq, sIn, g, b, 8192.0 * 76.0, out, sOut, B, VB,
        nullptr, nullptr, nullptr, nullptr, nullptr, nullptr, nullptr, nullptr, nullptr);
}

// ---------------------------------------------------------------------------
// FC1 via int8/dot4 (grid 2048, one row per wave). BIT-EXACT vs the f32
// version: quantized x,w are multiples of 1/8, so every product is a
// multiple of 1/64 and |row-sum*64| <= 740*64 = 47360 < 2^24 -> the old f32
// fma accumulation was EXACT; the int dot computes the same exact value in
// any order, and v = (float)acc * (1/64) is exact. z1, stats, and all
// downstream values are bit-identical.
// Lane layout: lane owns f = 12*lane .. 12*lane+11 (f padded to 768);
// 3 packed x-dwords, weights pre-packed (pack_fc1) as wp6[j*192 + lane*3+d].
// LDS drops 29.8KB -> 8.3KB.
// ---------------------------------------------------------------------------
__global__ __launch_bounds__(256) void k_fc1(
    const short* __restrict__ y5, const int* __restrict__ wp6,
    const double* __restrict__ statsIn,
    const float* __restrict__ g5, const float* __restrict__ b5,
    float* __restrict__ z1, double* __restrict__ statsOut, int B)
{
    __shared__ int wqi[1920];
    __shared__ float ts[20], tb[20];
    __shared__ float red[4][20];

    const int tid = threadIdx.x;
    const int bid = blockIdx.x;
    const int lane = tid & 63, wid = tid >> 6;

    for (int i = tid; i < 1920; i += 256) wqi[i] = wp6[i];
    if (tid < 20) {
        double S = 0.0, Q = 0.0;
#pragma unroll
        for (int s = 0; s < 8; s++) {
            S += statsIn[s * 40 + 2 * tid];
            Q += statsIn[s * 40 + 2 * tid + 1];
        }
        double N = 8192.0 * 37.0;
        double mean = S / N;
        double var  = Q / N - mean * mean;
        double inv  = 1.0 / sqrt(var + 1e-5);
        double sc   = (double)g5[tid] * inv;
        ts[tid] = (float)sc;                 // x already carries 1/64
        tb[tid] = (float)((double)b5[tid] - mean * sc);
    }
    __syncthreads();

    const int r = bid * 4 + wid;             // grid 2048 x 4 waves = 8192 rows
    const short* xr = y5 + (size_t)r * 800;  // 20ch x 40 padded
    const int f0 = lane * 12;

    // quantize + pack this lane's 12 activations
    int q[12];
#pragma unroll
    for (int u = 0; u < 12; u++) {
        int f = f0 + u;
        int val = 0;
        if (f < 740) {
            int c = f / 37, pos = f - c * 37;
            val = q8i((float)xr[c * 40 + pos] * 0.015625f, ts[c], tb[c]);
        }
        q[u] = val & 0xff;
    }
    int xp[3];
#pragma unroll
    for (int d = 0; d < 3; d++)
        xp[d] = q[4 * d] | (q[4 * d + 1] << 8) | (q[4 * d + 2] << 16) | (q[4 * d + 3] << 24);

    // 10 outputs x 3 dot4 each
    int ia[10];
#pragma unroll
    for (int j = 0; j < 10; j++) {
        int a = 0;
#pragma unroll
        for (int d = 0; d < 3; d++)
            a = dot4(xp[d], wqi[j * 192 + lane * 3 + d], a);
        ia[j] = a;
    }

    float tsum[10], tsq[10];
#pragma unroll
    for (int j = 0; j < 10; j++) {
        int a = ia[j];
        for (int off = 1; off < 64; off <<= 1) a += __shfl_xor(a, off, 64);
        float v = (float)a * 0.015625f;      // exact (/64 of int < 2^24)
        tsum[j] = v; tsq[j] = v * v;
        if (lane == j) z1[(size_t)r * 10 + j] = v;
    }
    if (lane == 0) {
#pragma unroll
        for (int j = 0; j < 10; j++) { red[wid][2 * j] = tsum[j]; red[wid][2 * j + 1] = tsq[j]; }
    }
    __syncthreads();
    if (tid < 20) {
        float v = red[0][tid] + red[1][tid] + red[2][tid] + red[3][tid];
        atomAddF64(&statsOut[(size_t)(bid & 7) * 20 + tid], (double)v);
    }
}

// ---------------------------------------------------------------------------
// FC2 fused single-block: R10 verbatim (pairwise z1 row interleave).
// ---------------------------------------------------------------------------
__global__ __launch_bounds__(256) void k_fc2(
    const float* __restrict__ z1, const float* __restrict__ fw2,
    const double* __restrict__ statsIn,
    const float* __restrict__ g6, const float* __restrict__ b6,
    const float* __restrict__ g7, const float* __restrict__ b7,
    float* __restrict__ outp, int B)
{
    __shared__ float zbuf[16384];
    __shared__ float ts7[10], tb7[10], wq2[20];
    __shared__ float fr[4][4];
    __shared__ float tr8[4];

    const int tid = threadIdx.x;
    const int lane = tid & 63, wid = tid >> 6;

    if (tid < 20) wq2[tid] = qwt(fw2[tid]);
    if (tid < 10) {
        double S = 0.0, Q = 0.0;
#pragma unroll
        for (int s = 0; s < 8; s++) {
            S += statsIn[s * 20 + 2 * tid];
            Q += statsIn[s * 20 + 2 * tid + 1];
        }
        double N = 8192.0;
        double mean = S / N;
        double var  = Q / N - mean * mean;
        double inv  = 1.0 / sqrt(var + 1e-5);
        double sc   = (double)g6[tid] * inv;
        ts7[tid] = (float)sc;
        tb7[tid] = (float)((double)b6[tid] - mean * sc);
    }
    __syncthreads();

    float s0 = 0.f, q0 = 0.f, s1 = 0.f, q1 = 0.f;
#pragma unroll 1
    for (int r = tid; r < B; r += 512) {
        const int r2 = r + 256;
        float a0 = 0.f, a1 = 0.f, c0 = 0.f, c1 = 0.f;
#pragma unroll
        for (int i = 0; i < 10; i++) {
            float xA = qact(z1[(size_t)r * 10 + i], ts7[i], tb7[i]);
            a0 = fmaf(xA, wq2[i], a0);
            a1 = fmaf(xA, wq2[10 + i], a1);
        }
#pragma unroll
        for (int i = 0; i < 10; i++) {
            float xB = qact(z1[(size_t)r2 * 10 + i], ts7[i], tb7[i]);
            c0 = fmaf(xB, wq2[i], c0);
            c1 = fmaf(xB, wq2[10 + i], c1);
        }
        zbuf[r * 2]      = a0;
        zbuf[r * 2 + 1]  = a1;
        zbuf[r2 * 2]     = c0;
        zbuf[r2 * 2 + 1] = c1;
        // stat-add order: r first, then r+256 (matches original sequence)
        s0 += a0; q0 = fmaf(a0, a0, q0);
        s1 += a1; q1 = fmaf(a1, a1, q1);
        s0 += c0; q0 = fmaf(c0, c0, q0);
        s1 += c1; q1 = fmaf(c1, c1, q1);
    }
    for (int off = 32; off > 0; off >>= 1) {
        s0 += __shfl_down(s0, off, 64); q0 += __shfl_down(q0, off, 64);
        s1 += __shfl_down(s1, off, 64); q1 += __shfl_down(q1, off, 64);
    }
    if (lane == 0) { fr[wid][0] = s0; fr[wid][1] = q0; fr[wid][2] = s1; fr[wid][3] = q1; }
    __syncthreads();
    if (tid < 2) {
        double S = 0.0, Q = 0.0;
        for (int w = 0; w < 4; w++) { S += (double)fr[w][2 * tid]; Q += (double)fr[w][2 * tid + 1]; }
        double N = (double)B;
        double mean = S / N;
        double var  = Q / N - mean * mean;
        double inv  = 1.0 / sqrt(var + 1e-5);
        double sc   = (double)g7[tid] * inv;
        tr8[tid]     = (float)sc;
        tr8[2 + tid] = (float)((double)b7[tid] - mean * sc);
    }
    __syncthreads();
    for (int i = tid; i < 2 * B; i += 256) {
        int c = i & 1;
        outp[i] = fmaf(zbuf[i], tr8[c], tr8[2 + c]);
    }
}

// ---------------------------------------------------------------------------
extern "C" void kernel_launch(void* const* d_in, const int* in_sizes, int n_in,
                              void* d_out, int out_size, void* d_ws, size_t ws_size,
                              hipStream_t stream)
{
    const float* x   = (const float*)d_in[0];
    const float* w1  = (const float*)d_in[1];
    const float* w2  = (const float*)d_in[2];
    const float* w3  = (const float*)d_in[3];
    const float* w4  = (const float*)d_in[4];
    const float* w5  = (const float*)d_in[5];
    const float* fw1 = (const float*)d_in[6];
    const float* fw2 = (const float*)d_in[7];
    const float *g[7], *bb[7];
    for (int i = 0; i < 7; i++) { g[i] = (const float*)d_in[8 + 2 * i]; bb[i] = (const float*)d_in[9 + 2 * i]; }

    char* ws = (char*)d_ws;
    size_t off = 0;
    auto alloc = [&](size_t bytes) -> void* {
        void* q = ws + off;
        off += (bytes + 255) & ~(size_t)255;
        return q;
    };
    short* y1 = (short*)alloc((size_t)8192 * 3 * 624 * 2);
    short* y2 = (short*)alloc((size_t)8192 * 5 * 312 * 2);
    short* y3 = (short*)alloc((size_t)8192 * 10 * 160 * 2);
    short* y4 = (short*)alloc((size_t)8192 * 20 * 80 * 2);
    short* y5 = (short*)alloc((size_t)8192 * 20 * 40 * 2);
    float* z1 = (float*)alloc((size_t)81920 * 4);
    int*   wp2 = (int*)alloc(256);  int* wp3 = (int*)alloc(256);
    int*   wp4 = (int*)alloc(1024); int* wp5 = (int*)alloc(2048);
    int*   wp6 = (int*)alloc(7680);   // fc1 packed weights (1920 dwords)
    // fp64 stat slots: 8 rows of 2C per layer, contiguous (1088 doubles)
    double* slots = (double*)alloc((size_t)1088 * 8);
    double* sl1 = slots;              // conv1: 8 x 6
    double* sl2 = sl1 + 8 * 6;        // conv2: 8 x 10
    double* sl3 = sl2 + 8 * 10;       // conv3: 8 x 20
    double* sl4 = sl3 + 8 * 20;       // conv4: 8 x 40
    double* sl5 = sl4 + 8 * 40;       // conv5: 8 x 40
    double* sl6 = sl5 + 8 * 40;       // fc1:   8 x 20

    const int B = 8192;

    hipMemsetAsync(slots, 0, (size_t)1088 * 8, stream);

    k_conv1<<<1024, 256, 0, stream>>>(x, y1, sl1, B, 2731,
                                      w1, w2, w3, w4, w5, wp2, wp3, wp4, wp5,
                                      fw1, wp6);
    k_conv2<<<1024, 256, 0, stream>>>(y1, wp2, sl1, g[0], bb[0], y2, sl2, B, 2048);
    k_conv3<<<1024, 256, 0, stream>>>(y2, wp3, sl2, g[1], bb[1], y3, sl3, B, 2048);
    k_conv4<<<1024, 256, 0, stream>>>(y3, wp4, sl3, g[2], bb[2], y4, sl4, B, 2048);
    k_conv5<<<1024, 256, 0, stream>>>(y4, wp5, sl4, g[3], bb[3], y5, sl5, B, 1024);
    k_fc1<<<2048, 256, 0, stream>>>(y5, wp6, sl5, g[4], bb[4], z1, sl6, B);
    k_fc2<<<1, 256, 0, stream>>>(z1, fw2, sl6, g[5], bb[5], g[6], bb[6],
                                 (float*)d_out, B);
}